// Round 6
// baseline (111.203 us; speedup 1.0000x reference)
//
#include <hip/hip_runtime.h>

#define N_NODES 10000
#define N_EDGES 640000
#define D 128
#define NQ (N_EDGES / 4)      // 160000 edge quads

#define NCHUNK 128            // scatter chunks (= scatter blocks)
#define QPC (NQ / NCHUNK)     // 1250 quads (5000 edges) per chunk, exact
#define GEMM_BLOCKS 157       // 64 nodes per block (MFMA)
#define GRID1 (NCHUNK + GEMM_BLOCKS)   // 285
#define NBUCK 1250            // bucket = row >> 3 (8 rows = one k2 block, exact)
#define CCAP 16               // per (bucket,chunk) cell cap: mean 4, +6 sigma; 128B cell
#define BSLOTS (NCHUNK * CCAP)// 2048 slots per bucket (16 KB)
#define SPILLCAP 5000         // worst case: a chunk spills every edge
#define CAP2 128              // per-row queue cap (mean 64, +8 sigma; slow path)
#define QPAD2 144             // CAP2 + 16 zero-pad
#define LSTR 136              // LDS row stride in ushorts (272B)

typedef unsigned int uint32;
typedef unsigned long long u64;
typedef unsigned short u16;
using short8 = __attribute__((ext_vector_type(8))) short;
using f32x4  = __attribute__((ext_vector_type(4))) float;

__device__ __forceinline__ uint32 f2bf_bits(float f) {
    uint32 u = __float_as_uint(f);
    return (u + 0x7FFFu + ((u >> 16) & 1u)) >> 16;   // RNE bf16 bits
}
__device__ __forceinline__ uint32 pack2(float lo, float hi) {
    return f2bf_bits(lo) | (f2bf_bits(hi) << 16);
}

// R14: R12->R13 arithmetic says ~28us of k2 is scan-invariant; candidate =
// LDS-atomic filter (all records funnel through 8 same-address LDS counters,
// which serialize in the CU's LDS pipe). Fix: bucket == k2 block (8 rows,
// NBUCK=1250), and an ATOMIC-FREE ballot-compaction filter: each wave owns
// 2 rows, scans the whole 16KB bucket (4-wave re-read = L1 hits), and
// computes queue slots via __ballot + popcount prefix. No LDS atomics, no
// cross-wave queue sharing, no barrier between filter and gather.
__global__ __launch_bounds__(256, 4) void gemm_scatter_kernel(
    const float* __restrict__ x, const float* __restrict__ w,
    const int* __restrict__ row, const int* __restrict__ col,
    const float* __restrict__ val,
    uint32* __restrict__ h2, int* __restrict__ cnts,
    int* __restrict__ spillcnt, uint2* __restrict__ bstore,
    uint2* __restrict__ spill)
{
    __shared__ __align__(16) u16 Ws[128 * LSTR];   // 34816 B (scatter aliases)
    const int t = threadIdx.x;

    if (blockIdx.x < NCHUNK) {
        // ---- chunk scatter: single pass, LDS counters only ----
        int* lcnt = (int*)Ws;             // [0..1249] bucket counts, [1250] spill
        for (int i = t; i <= NBUCK; i += 256) lcnt[i] = 0;
        __syncthreads();

        const int sb = blockIdx.x;
        const int4*   row4 = (const int4*)row;
        const int4*   col4 = (const int4*)col;
        const float4* val4 = (const float4*)val;
        const int i0 = sb * QPC;
        for (int i = i0 + t; i < i0 + QPC; i += 256) {
            int4 r = row4[i]; int4 c = col4[i]; float4 v = val4[i];
            #pragma unroll
            for (int e = 0; e < 4; ++e) {
                int rr = (e == 0) ? r.x : (e == 1) ? r.y : (e == 2) ? r.z : r.w;
                int cc = (e == 0) ? c.x : (e == 1) ? c.y : (e == 2) ? c.z : c.w;
                float vv = (e == 0) ? v.x : (e == 1) ? v.y : (e == 2) ? v.z : v.w;
                uint32 rc = (uint32)cc | (f2bf_bits(vv) << 16);
                int b = rr >> 3;
                int k = atomicAdd(&lcnt[b], 1);            // LDS only
                if (k < CCAP)
                    bstore[((size_t)(b * NCHUNK + sb) << 4) + k] =
                        make_uint2(rc, (uint32)rr);
                else {                                     // +6 sigma, ~never
                    int ks = atomicAdd(&lcnt[NBUCK], 1);
                    spill[(size_t)sb * SPILLCAP + ks] = make_uint2(rc, (uint32)rr);
                }
            }
        }
        __syncthreads();
        for (int b = t; b < NBUCK; b += 256) {
            int c = lcnt[b];
            cnts[b * NCHUNK + sb] = (c < CCAP) ? c : CCAP;  // unconditional
        }
        if (t == 0) spillcnt[sb] = lcnt[NBUCK];             // unconditional
    } else {
        // ---- MFMA GEMM: 64 rows/block, 4 waves x 16 rows x 128 cols.
        // A direct global->reg; W staged col-major in LDS (float4 loads).
        // C/D: col=lane&15, row=quad*4+reg (HW-verified).
        const int g = blockIdx.x - NCHUNK;
        const int lane = t & 63;
        const int wid  = t >> 6;
        const int q = lane >> 4, cl = lane & 15;

        const float4* w4 = (const float4*)w;
        #pragma unroll
        for (int i = 0; i < 8; ++i) {                 // stage W^T (128x128)
            int lin = t + i * 256;                    // m(k-pair) x qc(col-quad)
            int m  = lin >> 5;
            int qc = lin & 31;
            float4 r0 = w4[(2 * m) * 32 + qc];        // row 2m, cols 4qc..4qc+3
            float4 r1 = w4[(2 * m + 1) * 32 + qc];
            int c = qc * 4;
            *(uint32*)&Ws[(c + 0) * LSTR + 2 * m] = pack2(r0.x, r1.x);
            *(uint32*)&Ws[(c + 1) * LSTR + 2 * m] = pack2(r0.y, r1.y);
            *(uint32*)&Ws[(c + 2) * LSTR + 2 * m] = pack2(r0.z, r1.z);
            *(uint32*)&Ws[(c + 3) * LSTR + 2 * m] = pack2(r0.w, r1.w);
        }

        int gr = g * 64 + wid * 16 + cl;              // A-fragment row
        if (gr >= N_NODES) gr = N_NODES - 1;          // tail clamp (guarded write)
        const float* xrow = &x[(size_t)gr * D];
        float4 xv[8];
        #pragma unroll
        for (int kk = 0; kk < 4; ++kk) {
            xv[2 * kk]     = *(const float4*)&xrow[kk * 32 + q * 8];
            xv[2 * kk + 1] = *(const float4*)&xrow[kk * 32 + q * 8 + 4];
        }
        __syncthreads();

        f32x4 acc[8] = {};
        #pragma unroll
        for (int kk = 0; kk < 4; ++kk) {
            union { short8 s; uint32 u[4]; } af;
            float4 a = xv[2 * kk], b = xv[2 * kk + 1];
            af.u[0] = pack2(a.x, a.y); af.u[1] = pack2(a.z, a.w);
            af.u[2] = pack2(b.x, b.y); af.u[3] = pack2(b.z, b.w);
            #pragma unroll
            for (int ct = 0; ct < 8; ++ct) {
                short8 bf = *(const short8*)&Ws[(ct * 16 + cl) * LSTR + kk * 32 + q * 8];
                acc[ct] = __builtin_amdgcn_mfma_f32_16x16x32_bf16(af.s, bf, acc[ct], 0, 0, 0);
            }
        }
        #pragma unroll
        for (int reg = 0; reg < 4; ++reg) {
            int node = g * 64 + wid * 16 + q * 4 + reg;
            if (node < N_NODES) {
                uint32* base = h2 + (size_t)node * 64 + cl;
                #pragma unroll
                for (int ct = 0; ct < 4; ++ct)
                    base[ct * 16] = pack2(acc[ct][reg], acc[ct + 4][reg]);
            }
        }
    }
}

// k2: block == bucket (8 rows, 1250 blocks). Wave w owns rows (2w, 2w+1):
// scans all 2048 gated slots (32 iters; 4-wave re-read is L1-hot), builds its
// two row queues via ballot compaction (no atomics), then the proven
// branch-free depth-8 software-pipelined gather per row.
__global__ __launch_bounds__(256) void spmm_kernel(
    const uint2* __restrict__ bstore, const int* __restrict__ cnts,
    const int* __restrict__ spillcnt, const uint2* __restrict__ spill,
    const uint32* __restrict__ h2, const float* __restrict__ bias,
    float* __restrict__ out)
{
    __shared__ uint32 qbuf[8 * QPAD2];    // per-row queues (4608 B)
    __shared__ int lcnts[NCHUNK];         // bucket's per-chunk counts (512 B)
    __shared__ int sany;
    const int t = threadIdx.x;
    const int lane = t & 63;
    const int wid  = t >> 6;
    const int b  = blockIdx.x;            // bucket == block
    const int r0 = b * 8;

    if (t == 0) sany = 0;
    __syncthreads();
    if (t < NCHUNK) {
        lcnts[t] = cnts[b * NCHUNK + t];
        if (spillcnt[t] != 0) atomicAdd(&sany, 1);   // ~never taken
    }
    __syncthreads();

    // ---- ballot-compaction filter (atomic-free, wave-private) ----
    const size_t sbase = (size_t)b * BSLOTS;
    const uint32 da = (uint32)(wid * 2), db = da + 1;
    uint32* qa = &qbuf[(wid * 2) * QPAD2];
    uint32* qz = &qbuf[(wid * 2 + 1) * QPAD2];
    int ca = 0, cb = 0;
    const u64 pre = (lane == 63) ? ~0ull >> 1 : (1ull << lane) - 1;
    #pragma unroll 4
    for (int i = lane; i < BSLOTS; i += 64) {       // 32 uniform iterations
        int ch = i >> 4, sl = i & 15;
        uint32 rec = 0, d = 0xFFFFFFFFu;
        if (sl < lcnts[ch]) {
            uint2 e = bstore[sbase + i];
            rec = e.x; d = e.y - (uint32)r0;        // in [0,8) for valid recs
        }
        u64 ma = __ballot(d == da);
        u64 mb = __ballot(d == db);
        if (d == da) { int p = ca + __popcll(ma & pre); if (p < CAP2) qa[p] = rec; }
        if (d == db) { int p = cb + __popcll(mb & pre); if (p < CAP2) qz[p] = rec; }
        ca += __popcll(ma); cb += __popcll(mb);
    }
    // spill lists (expected empty; uniform, lane0 writes)
    if (sany) {
        for (int ch = 0; ch < NCHUNK; ++ch) {
            int sc = spillcnt[ch];
            for (int k = 0; k < sc; ++k) {
                uint2 e = spill[(size_t)ch * SPILLCAP + k];
                if (e.y == (uint32)r0 + da) { if (lane == 0 && ca < CAP2) qa[ca] = e.x; ca++; }
                if (e.y == (uint32)r0 + db) { if (lane == 0 && cb < CAP2) qz[cb] = e.x; cb++; }
            }
        }
    }

    // ---- per-row gather (wave-local; no block barrier needed) ----
    for (int half = 0; half < 2; ++half) {
        const int r = r0 + wid * 2 + half;
        uint32* qp = (half == 0) ? qa : qz;
        const int ntot = (half == 0) ? ca : cb;
        float a0 = 0.f, a1 = 0.f;

        if (ntot <= CAP2) {
            if (lane < 16) qp[ntot + lane] = 0;    // zero pad (val=+0.0 recs)
            __builtin_amdgcn_s_waitcnt(0);         // wave-local LDS drain

            const int npad = (ntot + 7) & ~7;
            uint32 rq0,rq1,rq2,rq3,rq4,rq5,rq6,rq7;
            uint32 hh0,hh1,hh2,hh3,hh4,hh5,hh6,hh7;
            rq0 = qp[0]; hh0 = h2[((rq0 & 0xFFFFu) << 6) + lane];
            rq1 = qp[1]; hh1 = h2[((rq1 & 0xFFFFu) << 6) + lane];
            rq2 = qp[2]; hh2 = h2[((rq2 & 0xFFFFu) << 6) + lane];
            rq3 = qp[3]; hh3 = h2[((rq3 & 0xFFFFu) << 6) + lane];
            rq4 = qp[4]; hh4 = h2[((rq4 & 0xFFFFu) << 6) + lane];
            rq5 = qp[5]; hh5 = h2[((rq5 & 0xFFFFu) << 6) + lane];
            rq6 = qp[6]; hh6 = h2[((rq6 & 0xFFFFu) << 6) + lane];
            rq7 = qp[7]; hh7 = h2[((rq7 & 0xFFFFu) << 6) + lane];

#define CONSUME_PREFETCH(RQ, HH, P)                                          \
    {                                                                        \
        a0 = fmaf(__uint_as_float(RQ & 0xFFFF0000u),                         \
                  __uint_as_float(HH << 16), a0);                            \
        a1 = fmaf(__uint_as_float(RQ & 0xFFFF0000u),                         \
                  __uint_as_float(HH & 0xFFFF0000u), a1);                    \
        uint32 rn = qp[j + 8 + P];                                           \
        RQ = rn; HH = h2[((rn & 0xFFFFu) << 6) + lane];                      \
    }

            for (int j = 0; j < npad; j += 8) {
                CONSUME_PREFETCH(rq0, hh0, 0)
                CONSUME_PREFETCH(rq1, hh1, 1)
                CONSUME_PREFETCH(rq2, hh2, 2)
                CONSUME_PREFETCH(rq3, hh3, 3)
                CONSUME_PREFETCH(rq4, hh4, 4)
                CONSUME_PREFETCH(rq5, hh5, 5)
                CONSUME_PREFETCH(rq6, hh6, 6)
                CONSUME_PREFETCH(rq7, hh7, 7)
            }
#undef CONSUME_PREFETCH
        } else {
            // slow path (row > CAP2 records; ~never): rescan bucket + spills.
            for (int i = 0; i < BSLOTS; ++i) {
                int ch = i >> 4, sl = i & 15;
                if (sl < lcnts[ch]) {
                    uint2 e = bstore[sbase + i];
                    if (e.y == (uint32)r) {
                        uint32 hv = h2[((e.x & 0xFFFFu) << 6) + lane];
                        a0 = fmaf(__uint_as_float(e.x & 0xFFFF0000u),
                                  __uint_as_float(hv << 16), a0);
                        a1 = fmaf(__uint_as_float(e.x & 0xFFFF0000u),
                                  __uint_as_float(hv & 0xFFFF0000u), a1);
                    }
                }
            }
            for (int ch = 0; ch < NCHUNK; ++ch) {
                int sc = spillcnt[ch];
                for (int k = 0; k < sc; ++k) {
                    uint2 e = spill[(size_t)ch * SPILLCAP + k];
                    if (e.y == (uint32)r) {
                        uint32 hv = h2[((e.x & 0xFFFFu) << 6) + lane];
                        a0 = fmaf(__uint_as_float(e.x & 0xFFFF0000u),
                                  __uint_as_float(hv << 16), a0);
                        a1 = fmaf(__uint_as_float(e.x & 0xFFFF0000u),
                                  __uint_as_float(hv & 0xFFFF0000u), a1);
                    }
                }
            }
        }

        out[(size_t)r * D + lane]      = a0 + bias[lane];
        out[(size_t)r * D + 64 + lane] = a1 + bias[lane + 64];
    }
}

extern "C" void kernel_launch(void* const* d_in, const int* in_sizes, int n_in,
                              void* d_out, int out_size, void* d_ws, size_t ws_size,
                              hipStream_t stream)
{
    const float* x    = (const float*)d_in[0];
    const float* aval = (const float*)d_in[1];
    const float* w    = (const float*)d_in[2];
    const float* bias = (const float*)d_in[3];
    const int* arow   = (const int*)d_in[4];
    const int* acol   = (const int*)d_in[5];

    char* ws = (char*)d_ws;
    uint32* h2       = (uint32*)(ws);              //  2,560,000 B
    int*    cnts     = (int*)(ws + 2560000);       //    640,000 B (1250 x 128)
    int*    spillcnt = (int*)(ws + 3200000);       //        512 B (128)
    uint2*  bstore   = (uint2*)(ws + 3200512);     // 20,480,000 B (1250x128x16x8)
    uint2*  spill    = (uint2*)(ws + 23680512);    //  5,120,000 B (128x5000x8)
    // total 28,800,512 B; no memset: cnts/spillcnt written unconditionally

    gemm_scatter_kernel<<<GRID1, 256, 0, stream>>>(
        x, w, arow, acol, aval, h2, cnts, spillcnt, bstore, spill);
    spmm_kernel<<<NBUCK, 256, 0, stream>>>(
        bstore, cnts, spillcnt, spill, h2, bias, (float*)d_out);
}

// Round 7
// 105.534 us; speedup vs baseline: 1.0537x; 1.0537x over previous
//
#include <hip/hip_runtime.h>

#define N_NODES 10000
#define N_EDGES 640000
#define D 128
#define NQ (N_EDGES / 4)      // 160000 edge quads

#define NCHUNK 64             // scatter chunks (= scatter blocks)
#define QPC (NQ / NCHUNK)     // 2500 quads (10000 edges) per chunk, exact
#define GEMM_BLOCKS 157       // 64 nodes per block (MFMA)
#define GRID1 (NCHUNK + GEMM_BLOCKS)   // 221
#define RCAP 8                // per (row,chunk) cell cap: mean 1.0, P(>8)~1e-6
#define SPILLCAP 10000        // worst case: a chunk spills every edge
#define CAP2 128              // per-row queue cap (mean 64, +8 sigma; slow path)
#define QPAD2 144             // CAP2 + 16 zero-pad
#define LSTR 136              // LDS row stride in ushorts (272B)

typedef unsigned int uint32;
typedef unsigned long long u64;
typedef unsigned short u16;
typedef unsigned char u8;
using short8 = __attribute__((ext_vector_type(8))) short;
using f32x4  = __attribute__((ext_vector_type(4))) float;

__device__ __forceinline__ uint32 f2bf_bits(float f) {
    uint32 u = __float_as_uint(f);
    return (u + 0x7FFFu + ((u >> 16) & 1u)) >> 16;   // RNE bf16 bits
}
__device__ __forceinline__ uint32 pack2(float lo, float hi) {
    return f2bf_bits(lo) | (f2bf_bits(hi) << 16);
}

// R15: R13/R14 showed k2's ~30us is the per-record FILTER (route/compare
// work), not LDS-atomic contention (R14 ballot regressed) and not scan
// volume alone (R13). Fix: make the filter vanish. k1 bins records into
// PER-ROW cells bstore[row][chunk][8] (4B records: col|bf16val, row
// implicit) via a 10000-counter LDS histogram (uncontended). k2 builds each
// row queue by deterministic prefix-compaction: lane=chunk, u8 count load,
// 6-step shfl_up prefix, one unconditional 32B cell read (row strip is 2KB
// contiguous, L3-hot), <=8 predicated LDS writes. Zero compares, zero
// atomics, zero barriers in k2. Then the proven depth-8 pipelined gather.
__global__ __launch_bounds__(256, 4) void gemm_scatter_kernel(
    const float* __restrict__ x, const float* __restrict__ w,
    const int* __restrict__ row, const int* __restrict__ col,
    const float* __restrict__ val,
    uint32* __restrict__ h2, u8* __restrict__ cnts2,
    int* __restrict__ spillcnt, uint32* __restrict__ bstore,
    uint2* __restrict__ spill)
{
    __shared__ __align__(16) int SH[N_NODES];      // 40000 B (hist / Ws alias)
    __shared__ int spillc;
    const int t = threadIdx.x;

    if (blockIdx.x < NCHUNK) {
        // ---- chunk scatter: single pass, per-row LDS histogram ----
        int* hist = SH;
        for (int i = t; i < N_NODES; i += 256) hist[i] = 0;
        if (t == 0) spillc = 0;
        __syncthreads();

        const int sb = blockIdx.x;
        const int4*   row4 = (const int4*)row;
        const int4*   col4 = (const int4*)col;
        const float4* val4 = (const float4*)val;
        const int i0 = sb * QPC;
        for (int i = i0 + t; i < i0 + QPC; i += 256) {
            int4 r = row4[i]; int4 c = col4[i]; float4 v = val4[i];
            #pragma unroll
            for (int e = 0; e < 4; ++e) {
                int rr = (e == 0) ? r.x : (e == 1) ? r.y : (e == 2) ? r.z : r.w;
                int cc = (e == 0) ? c.x : (e == 1) ? c.y : (e == 2) ? c.z : c.w;
                float vv = (e == 0) ? v.x : (e == 1) ? v.y : (e == 2) ? v.z : v.w;
                uint32 rc = (uint32)cc | (f2bf_bits(vv) << 16);
                int k = atomicAdd(&hist[rr], 1);           // LDS, ~no contention
                if (k < RCAP)
                    bstore[(size_t)rr * (NCHUNK * RCAP) + sb * RCAP + k] = rc;
                else {                                     // P ~ 1e-6, ~never
                    int ks = atomicAdd(&spillc, 1);
                    spill[(size_t)sb * SPILLCAP + ks] = make_uint2(rc, (uint32)rr);
                }
            }
        }
        __syncthreads();
        for (int r = t; r < N_NODES; r += 256) {           // coalesced u8 writes
            int c = hist[r];
            cnts2[(size_t)sb * N_NODES + r] = (u8)((c < RCAP) ? c : RCAP);
        }
        if (t == 0) spillcnt[sb] = spillc;                 // unconditional
    } else {
        // ---- MFMA GEMM: 64 rows/block, 4 waves x 16 rows x 128 cols.
        // A direct global->reg; W staged col-major in LDS (float4 loads).
        // C/D: col=lane&15, row=quad*4+reg (HW-verified).
        u16* Ws = (u16*)SH;
        const int g = blockIdx.x - NCHUNK;
        const int lane = t & 63;
        const int wid  = t >> 6;
        const int q = lane >> 4, cl = lane & 15;

        const float4* w4 = (const float4*)w;
        #pragma unroll
        for (int i = 0; i < 8; ++i) {                 // stage W^T (128x128)
            int lin = t + i * 256;                    // m(k-pair) x qc(col-quad)
            int m  = lin >> 5;
            int qc = lin & 31;
            float4 r0 = w4[(2 * m) * 32 + qc];        // row 2m, cols 4qc..4qc+3
            float4 r1 = w4[(2 * m + 1) * 32 + qc];
            int c = qc * 4;
            *(uint32*)&Ws[(c + 0) * LSTR + 2 * m] = pack2(r0.x, r1.x);
            *(uint32*)&Ws[(c + 1) * LSTR + 2 * m] = pack2(r0.y, r1.y);
            *(uint32*)&Ws[(c + 2) * LSTR + 2 * m] = pack2(r0.z, r1.z);
            *(uint32*)&Ws[(c + 3) * LSTR + 2 * m] = pack2(r0.w, r1.w);
        }

        int gr = g * 64 + wid * 16 + cl;              // A-fragment row
        if (gr >= N_NODES) gr = N_NODES - 1;          // tail clamp (guarded write)
        const float* xrow = &x[(size_t)gr * D];
        float4 xv[8];
        #pragma unroll
        for (int kk = 0; kk < 4; ++kk) {
            xv[2 * kk]     = *(const float4*)&xrow[kk * 32 + q * 8];
            xv[2 * kk + 1] = *(const float4*)&xrow[kk * 32 + q * 8 + 4];
        }
        __syncthreads();

        f32x4 acc[8] = {};
        #pragma unroll
        for (int kk = 0; kk < 4; ++kk) {
            union { short8 s; uint32 u[4]; } af;
            float4 a = xv[2 * kk], b = xv[2 * kk + 1];
            af.u[0] = pack2(a.x, a.y); af.u[1] = pack2(a.z, a.w);
            af.u[2] = pack2(b.x, b.y); af.u[3] = pack2(b.z, b.w);
            #pragma unroll
            for (int ct = 0; ct < 8; ++ct) {
                short8 bf = *(const short8*)&Ws[(ct * 16 + cl) * LSTR + kk * 32 + q * 8];
                acc[ct] = __builtin_amdgcn_mfma_f32_16x16x32_bf16(af.s, bf, acc[ct], 0, 0, 0);
            }
        }
        #pragma unroll
        for (int reg = 0; reg < 4; ++reg) {
            int node = g * 64 + wid * 16 + q * 4 + reg;
            if (node < N_NODES) {
                uint32* base = h2 + (size_t)node * 64 + cl;
                #pragma unroll
                for (int ct = 0; ct < 4; ++ct)
                    base[ct * 16] = pack2(acc[ct][reg], acc[ct + 4][reg]);
            }
        }
    }
}

// k2: 8 rows/block (1250 blocks), wave w owns rows (2w, 2w+1) sequentially.
// Queue build per row: lane=chunk, prefix-compaction (see R15 header comment).
// Entirely wave-local: no barriers. Gather: proven branch-free depth-8
// software-pipelined loop (8 L2 gathers always in flight).
__global__ __launch_bounds__(256) void spmm_kernel(
    const uint32* __restrict__ bstore, const u8* __restrict__ cnts2,
    const int* __restrict__ spillcnt, const uint2* __restrict__ spill,
    const uint32* __restrict__ h2, const float* __restrict__ bias,
    float* __restrict__ out)
{
    __shared__ uint32 qbuf[8 * QPAD2];    // per-(wave,half) queues (4608 B)
    const int t = threadIdx.x;
    const int lane = t & 63;
    const int wid  = t >> 6;
    const int r0 = blockIdx.x * 8;

    const bool anyspill = __ballot(spillcnt[lane & 63] != 0) != 0ull;

    for (int half = 0; half < 2; ++half) {
        const int r = r0 + wid * 2 + half;
        uint32* qp = &qbuf[(wid * 2 + half) * QPAD2];

        // ---- prefix-compaction queue build (atomic-free, compare-free) ----
        int c = cnts2[(size_t)lane * N_NODES + r];        // lane = chunk
        int p = c;
        #pragma unroll
        for (int d = 1; d < 64; d <<= 1) {
            int v = __shfl_up(p, d);
            if (lane >= d) p += v;
        }
        int ntot = __shfl(p, 63);
        int base = p - c;
        const uint32* cell = &bstore[(size_t)r * (NCHUNK * RCAP) + lane * RCAP];
        uint4 c0 = *(const uint4*)cell;                   // unconditional 32B
        uint4 c1 = *(const uint4*)(cell + 4);             // (strip is 2KB contig)
        if (c > 0 && base + 0 < CAP2) qp[base + 0] = c0.x;
        if (c > 1 && base + 1 < CAP2) qp[base + 1] = c0.y;
        if (c > 2 && base + 2 < CAP2) qp[base + 2] = c0.z;
        if (c > 3 && base + 3 < CAP2) qp[base + 3] = c0.w;
        if (c > 4 && base + 4 < CAP2) qp[base + 4] = c1.x;
        if (c > 5 && base + 5 < CAP2) qp[base + 5] = c1.y;
        if (c > 6 && base + 6 < CAP2) qp[base + 6] = c1.z;
        if (c > 7 && base + 7 < CAP2) qp[base + 7] = c1.w;

        if (anyspill) {                                   // ~never taken
            for (int ch = 0; ch < NCHUNK; ++ch) {
                int sc = spillcnt[ch];
                for (int k = 0; k < sc; ++k) {
                    uint2 e = spill[(size_t)ch * SPILLCAP + k];
                    if (e.y == (uint32)r) {
                        if (lane == 0 && ntot < CAP2) qp[ntot] = e.x;
                        ntot++;
                    }
                }
            }
        }

        float a0 = 0.f, a1 = 0.f;
        if (ntot <= CAP2) {
            if (lane < 16) qp[ntot + lane] = 0;    // zero pad (val=+0.0 recs)
            __builtin_amdgcn_s_waitcnt(0);         // wave-local LDS drain

            const int npad = (ntot + 7) & ~7;
            uint32 rq0,rq1,rq2,rq3,rq4,rq5,rq6,rq7;
            uint32 hh0,hh1,hh2,hh3,hh4,hh5,hh6,hh7;
            rq0 = qp[0]; hh0 = h2[((rq0 & 0xFFFFu) << 6) + lane];
            rq1 = qp[1]; hh1 = h2[((rq1 & 0xFFFFu) << 6) + lane];
            rq2 = qp[2]; hh2 = h2[((rq2 & 0xFFFFu) << 6) + lane];
            rq3 = qp[3]; hh3 = h2[((rq3 & 0xFFFFu) << 6) + lane];
            rq4 = qp[4]; hh4 = h2[((rq4 & 0xFFFFu) << 6) + lane];
            rq5 = qp[5]; hh5 = h2[((rq5 & 0xFFFFu) << 6) + lane];
            rq6 = qp[6]; hh6 = h2[((rq6 & 0xFFFFu) << 6) + lane];
            rq7 = qp[7]; hh7 = h2[((rq7 & 0xFFFFu) << 6) + lane];

#define CONSUME_PREFETCH(RQ, HH, P)                                          \
    {                                                                        \
        a0 = fmaf(__uint_as_float(RQ & 0xFFFF0000u),                         \
                  __uint_as_float(HH << 16), a0);                            \
        a1 = fmaf(__uint_as_float(RQ & 0xFFFF0000u),                         \
                  __uint_as_float(HH & 0xFFFF0000u), a1);                    \
        uint32 rn = qp[j + 8 + P];                                           \
        RQ = rn; HH = h2[((rn & 0xFFFFu) << 6) + lane];                      \
    }

            for (int j = 0; j < npad; j += 8) {
                CONSUME_PREFETCH(rq0, hh0, 0)
                CONSUME_PREFETCH(rq1, hh1, 1)
                CONSUME_PREFETCH(rq2, hh2, 2)
                CONSUME_PREFETCH(rq3, hh3, 3)
                CONSUME_PREFETCH(rq4, hh4, 4)
                CONSUME_PREFETCH(rq5, hh5, 5)
                CONSUME_PREFETCH(rq6, hh6, 6)
                CONSUME_PREFETCH(rq7, hh7, 7)
            }
#undef CONSUME_PREFETCH
        } else {
            // slow path (row > CAP2 records; ~never): rescan row cells + spills.
            for (int ch = 0; ch < NCHUNK; ++ch) {
                int c2 = cnts2[(size_t)ch * N_NODES + r];
                for (int k = 0; k < c2; ++k) {
                    uint32 rec = bstore[(size_t)r * (NCHUNK * RCAP) + ch * RCAP + k];
                    uint32 hv = h2[((rec & 0xFFFFu) << 6) + lane];
                    a0 = fmaf(__uint_as_float(rec & 0xFFFF0000u),
                              __uint_as_float(hv << 16), a0);
                    a1 = fmaf(__uint_as_float(rec & 0xFFFF0000u),
                              __uint_as_float(hv & 0xFFFF0000u), a1);
                }
            }
            for (int ch = 0; ch < NCHUNK; ++ch) {
                int sc = spillcnt[ch];
                for (int k = 0; k < sc; ++k) {
                    uint2 e = spill[(size_t)ch * SPILLCAP + k];
                    if (e.y == (uint32)r) {
                        uint32 hv = h2[((e.x & 0xFFFFu) << 6) + lane];
                        a0 = fmaf(__uint_as_float(e.x & 0xFFFF0000u),
                                  __uint_as_float(hv << 16), a0);
                        a1 = fmaf(__uint_as_float(e.x & 0xFFFF0000u),
                                  __uint_as_float(hv & 0xFFFF0000u), a1);
                    }
                }
            }
        }

        out[(size_t)r * D + lane]      = a0 + bias[lane];
        out[(size_t)r * D + 64 + lane] = a1 + bias[lane + 64];
    }
}

extern "C" void kernel_launch(void* const* d_in, const int* in_sizes, int n_in,
                              void* d_out, int out_size, void* d_ws, size_t ws_size,
                              hipStream_t stream)
{
    const float* x    = (const float*)d_in[0];
    const float* aval = (const float*)d_in[1];
    const float* w    = (const float*)d_in[2];
    const float* bias = (const float*)d_in[3];
    const int* arow   = (const int*)d_in[4];
    const int* acol   = (const int*)d_in[5];

    char* ws = (char*)d_ws;
    uint32* h2       = (uint32*)(ws);              //  2,560,000 B
    u8*     cnts2    = (u8*)(ws + 2560000);        //    640,000 B (64 x 10000)
    int*    spillcnt = (int*)(ws + 3200000);       //        256 B (64) +pad
    uint32* bstore   = (uint32*)(ws + 3200512);    // 20,480,000 B (10000x64x8x4)
    uint2*  spill    = (uint2*)(ws + 23680512);    //  5,120,000 B (64x10000x8)
    // total 28,800,512 B (same as R14, proven); no memset: cnts2/spillcnt
    // written unconditionally by k1.

    gemm_scatter_kernel<<<GRID1, 256, 0, stream>>>(
        x, w, arow, acol, aval, h2, cnts2, spillcnt, bstore, spill);
    spmm_kernel<<<N_NODES / 8, 256, 0, stream>>>(
        bstore, cnts2, spillcnt, spill, h2, bias, (float*)d_out);
}